// Round 1
// baseline (3649.653 us; speedup 1.0000x reference)
//
#include <hip/hip_runtime.h>
#include <float.h>
#include <stdint.h>

#define NB    8       // batch
#define NCH   256     // channels C (= GEMM K)
#define NPIX  4096    // H*W = 64*64
#define NTILE 32      // 4096 / 128 tiles per dim

// ---------------- workspace layout (bytes) ----------------
#define OFF_FNT   ((size_t)0)            // [B][C][N] f32 normalized f   (33554432)
#define OFF_FANT  ((size_t)33554432)     // [B][C][N] f32 normalized f_aug
#define OFF_ROWPV ((size_t)67108864)     // [B][NT][N][3] f32 row-top3 partial vals (12582912)
#define OFF_ROWPI ((size_t)79691776)     // [B][NT][N][3] i32 row-top3 partial idx
#define OFF_COLPV ((size_t)92274688)
#define OFF_COLPI ((size_t)104857600)
#define OFF_DNF   ((size_t)117440512)    // [B][N] f32 max(||f_n||,eps)     (131072)
#define OFF_DNFA  ((size_t)117571584)
#define OFF_LAB1  ((size_t)117702656)    // [B][N] i32 downsampled label   (131072)
#define OFF_LAB2  ((size_t)117833728)
#define OFF_ROWT3 ((size_t)117964800)    // [B][N][3] i32 final row top3   (393216)
#define OFF_COLT3 ((size_t)118358016)
#define OFF_FLAG1 ((size_t)118751232)    // [B][N] i32 lab | stable<<3     (131072)
#define OFF_FLAG2 ((size_t)118882304)
#define OFF_CNTS  ((size_t)119013376)    // [view][kind][B][4] i32         (512)
#define OFF_PACC  ((size_t)119013888)    // [view][B][4][kind][C] f32      (131072)
#define WS_NEEDED ((size_t)119144960)

// ---------------- (val desc, idx asc) top-3 insertion — matches lax.top_k ties
__device__ __forceinline__ bool pb_better(float v, int i, float w, int iw) {
  return (v > w) || (v == w && i < iw);
}
__device__ __forceinline__ void pb_ins3(float v, int i, float tv[3], int ti[3]) {
  if (!pb_better(v, i, tv[2], ti[2])) return;
  if (pb_better(v, i, tv[1], ti[1])) {
    if (pb_better(v, i, tv[0], ti[0])) {
      tv[2] = tv[1]; ti[2] = ti[1]; tv[1] = tv[0]; ti[1] = ti[0]; tv[0] = v; ti[0] = i;
    } else { tv[2] = tv[1]; ti[2] = ti[1]; tv[1] = v; ti[1] = i; }
  } else { tv[2] = v; ti[2] = i; }
}

// ---------------- K0: nearest-downsample labels 256x256 -> 64x64 ----------------
__global__ void pb_dslab(const int* __restrict__ lab, const int* __restrict__ laba,
                         int* __restrict__ o1, int* __restrict__ o2) {
  int gid = blockIdx.x * 256 + threadIdx.x;          // b*N + n
  const int* src = blockIdx.y ? laba : lab;
  int* dst = blockIdx.y ? o2 : o1;
  int b = gid >> 12, n = gid & 4095;
  int y = n >> 6, x = n & 63;
  dst[gid] = src[((size_t)b << 16) + (y << 10) + (x << 2)];   // label[b,0,4y,4x]
}

// ---------------- K1: per-pixel L2 norm denominators ----------------
__global__ void pb_norm(const float* __restrict__ f, const float* __restrict__ fa,
                        float* __restrict__ dnf, float* __restrict__ dnfa) {
  const float* src = blockIdx.z ? fa : f;
  float* dst = blockIdx.z ? dnfa : dnf;
  int b = blockIdx.y;
  int n = blockIdx.x * 256 + threadIdx.x;
  const float* base = src + ((size_t)b << 20) + n;   // f[b][c][n], stride N over c
  float ss = 0.f;
#pragma unroll 4
  for (int c = 0; c < NCH; ++c) { float v = base[(size_t)c << 12]; ss = fmaf(v, v, ss); }
  dst[(b << 12) + n] = fmaxf(sqrtf(ss), 1e-12f);
}

// ---------------- K2: normalized copies (same [b][c][n] layout as input) ----------------
__global__ void pb_scale(const float* __restrict__ f, const float* __restrict__ fa,
                         const float* __restrict__ dnf, const float* __restrict__ dnfa,
                         float* __restrict__ fnT, float* __restrict__ fanT) {
  const float* src = blockIdx.y ? fa : f;
  const float* dn  = blockIdx.y ? dnfa : dnf;
  float* dst = blockIdx.y ? fanT : fnT;
  size_t gid = (size_t)blockIdx.x * 256 + threadIdx.x;   // float4 index
  size_t e = gid << 2;
  int b = (int)(e >> 20), n = (int)(e & 4095);
  float4 v = *(const float4*)(src + e);
  float4 d = *(const float4*)(dn + (b << 12) + n);
  float4 o = make_float4(v.x / d.x, v.y / d.y, v.z / d.z, v.w / d.w);
  *(float4*)(dst + e) = o;
}

// ---------------- K3: fused fp32 GEMM (sim tile) + per-tile row/col top-3 ----------------
// S[p][q] = sum_c fnT[b][c][p] * fanT[b][c][q]; 128x128 tile per WG, BK=16, 8x8/thread.
__global__ __launch_bounds__(256, 2) void pb_gemm_top3(
    const float* __restrict__ fnT, const float* __restrict__ fanT,
    float* __restrict__ rowPV, int* __restrict__ rowPI,
    float* __restrict__ colPV, int* __restrict__ colPI) {
  __shared__ float smem[16384];          // union: staging 8K floats / output tile 16K floats
  const int tid = threadIdx.x;
  const int tx = tid & 15, ty = tid >> 4;
  const int b = blockIdx.z;
  const int p0 = blockIdx.y << 7, q0 = blockIdx.x << 7;
  const float* A  = fnT  + ((size_t)b << 20);
  const float* Bg = fanT + ((size_t)b << 20);

  float acc[8][8];
#pragma unroll
  for (int i = 0; i < 8; ++i)
#pragma unroll
    for (int j = 0; j < 8; ++j) acc[i][j] = 0.f;

  float* As = smem;          // [2][16][128] k-major
  float* Bs = smem + 4096;   // [2][16][128]
  float4 ra[2], rb[2];

  // prologue: stage k-tile 0
#pragma unroll
  for (int i = 0; i < 2; ++i) {
    int u = i * 256 + tid;                       // float4 unit: row=u>>5, col4=u&31
    ra[i] = *(const float4*)(A  + ((size_t)(u >> 5) << 12) + p0 + ((u & 31) << 2));
    rb[i] = *(const float4*)(Bg + ((size_t)(u >> 5) << 12) + q0 + ((u & 31) << 2));
  }
#pragma unroll
  for (int i = 0; i < 2; ++i) {
    int u = i * 256 + tid;
    *(float4*)(As + (u << 2)) = ra[i];
    *(float4*)(Bs + (u << 2)) = rb[i];
  }
  __syncthreads();

  int cur = 0;
#pragma unroll 1
  for (int kt = 0; kt < 16; ++kt) {
    if (kt < 15) {                               // prefetch next k-tile into regs
#pragma unroll
      for (int i = 0; i < 2; ++i) {
        int u = i * 256 + tid;
        int kr = (kt + 1) * 16 + (u >> 5);
        ra[i] = *(const float4*)(A  + ((size_t)kr << 12) + p0 + ((u & 31) << 2));
        rb[i] = *(const float4*)(Bg + ((size_t)kr << 12) + q0 + ((u & 31) << 2));
      }
    }
    const float* Ab = As + cur * 2048;
    const float* Bb = Bs + cur * 2048;
#pragma unroll
    for (int k = 0; k < 16; ++k) {
      float a[8], bb[8];
      *(float4*)&a[0]  = *(const float4*)(Ab + k * 128 + ty * 8);
      *(float4*)&a[4]  = *(const float4*)(Ab + k * 128 + ty * 8 + 4);
      *(float4*)&bb[0] = *(const float4*)(Bb + k * 128 + tx * 8);
      *(float4*)&bb[4] = *(const float4*)(Bb + k * 128 + tx * 8 + 4);
#pragma unroll
      for (int i = 0; i < 8; ++i)
#pragma unroll
        for (int j = 0; j < 8; ++j) acc[i][j] = fmaf(a[i], bb[j], acc[i][j]);
    }
    if (kt < 15) {
      int nb = cur ^ 1;
#pragma unroll
      for (int i = 0; i < 2; ++i) {
        int u = i * 256 + tid;
        *(float4*)(As + nb * 2048 + (u << 2)) = ra[i];
        *(float4*)(Bs + nb * 2048 + (u << 2)) = rb[i];
      }
      __syncthreads();
      cur = nb;
    }
  }

  __syncthreads();                               // everyone done reading LDS
  // dump 128x128 tile (no pad: exactly 64 KB)
#pragma unroll
  for (int i = 0; i < 8; ++i) {
    *(float4*)&smem[(ty * 8 + i) * 128 + tx * 8]     = make_float4(acc[i][0], acc[i][1], acc[i][2], acc[i][3]);
    *(float4*)&smem[(ty * 8 + i) * 128 + tx * 8 + 4] = make_float4(acc[i][4], acc[i][5], acc[i][6], acc[i][7]);
  }
  __syncthreads();

  float tv[3]; int ti[3];
  tv[0] = tv[1] = tv[2] = -FLT_MAX;
  ti[0] = ti[1] = ti[2] = 0x7fffffff;
  if (tid < 128) {                               // row scan, staggered to avoid 64-way bank conflict
    int r = tid;
#pragma unroll 4
    for (int j = 0; j < 128; ++j) {
      int jj = (j + r) & 127;
      pb_ins3(smem[r * 128 + jj], jj, tv, ti);
    }
    size_t base = ((((size_t)b * NTILE + blockIdx.x) * NPIX) + p0 + r) * 3;
    rowPV[base + 0] = tv[0]; rowPV[base + 1] = tv[1]; rowPV[base + 2] = tv[2];
    rowPI[base + 0] = q0 + ti[0]; rowPI[base + 1] = q0 + ti[1]; rowPI[base + 2] = q0 + ti[2];
  } else {                                       // column scan (2-way conflict: free)
    int c = tid - 128;
#pragma unroll 4
    for (int i = 0; i < 128; ++i) pb_ins3(smem[i * 128 + c], i, tv, ti);
    size_t base = ((((size_t)b * NTILE + blockIdx.y) * NPIX) + q0 + c) * 3;
    colPV[base + 0] = tv[0]; colPV[base + 1] = tv[1]; colPV[base + 2] = tv[2];
    colPI[base + 0] = p0 + ti[0]; colPI[base + 1] = p0 + ti[1]; colPI[base + 2] = p0 + ti[2];
  }
}

// ---------------- K4: merge 32 tile partials -> final top-3 indices ----------------
__global__ void pb_merge(const float* __restrict__ pv, const int* __restrict__ pi,
                         int* __restrict__ outI) {
  int gid = blockIdx.x * 256 + threadIdx.x;      // b*N + pixel
  int b = gid >> 12, p = gid & 4095;
  float tv[3]; int ti[3];
  tv[0] = tv[1] = tv[2] = -FLT_MAX;
  ti[0] = ti[1] = ti[2] = 0x7fffffff;
#pragma unroll 1
  for (int t = 0; t < NTILE; ++t) {
    size_t base = (((size_t)b * NTILE + t) * NPIX + p) * 3;
#pragma unroll
    for (int s = 0; s < 3; ++s) pb_ins3(pv[base + s], pi[base + s], tv, ti);
  }
  outI[(size_t)gid * 3 + 0] = ti[0];
  outI[(size_t)gid * 3 + 1] = ti[1];
  outI[(size_t)gid * 3 + 2] = ti[2];
}

// ---------------- K5: stability flags + class counts ----------------
__global__ void pb_stable(const int* __restrict__ lab1, const int* __restrict__ lab2,
                          const int* __restrict__ rowT3, const int* __restrict__ colT3,
                          int* __restrict__ flag1, int* __restrict__ flag2,
                          int* __restrict__ cnts) {
  __shared__ int sc[16];                         // view*8 + kind*4 + cls (kind0=stable)
  int tid = threadIdx.x;
  if (tid < 16) sc[tid] = 0;
  __syncthreads();
  int b = blockIdx.y;
  int gid = (b << 12) + blockIdx.x * 256 + tid;

  // view 1: pixels of f; topk over aug (rows), nn = col-argmax
  int l1 = lab1[gid];
  bool s1 = false;
#pragma unroll
  for (int j = 0; j < 3; ++j) {
    int q  = rowT3[(size_t)gid * 3 + j];               // aug pixel
    int pp = colT3[(((size_t)b << 12) + q) * 3];       // its nearest f pixel (col argmax)
    s1 |= (lab1[(b << 12) + pp] == l1);
  }
  s1 = s1 && (l1 != 4);
  flag1[gid] = l1 | (s1 ? 8 : 0);
  if (l1 < 4) {
    atomicAdd(&sc[4 + l1], 1);
    if (s1) atomicAdd(&sc[0 + l1], 1);
  }

  // view 2: pixels of f_aug; topk = col-top3 of sim, nn = row-argmax
  int l2 = lab2[gid];
  bool s2 = false;
#pragma unroll
  for (int j = 0; j < 3; ++j) {
    int m  = colT3[(size_t)gid * 3 + j];               // f pixel
    int rr = rowT3[(((size_t)b << 12) + m) * 3];       // its nearest aug pixel (row argmax)
    s2 |= (lab2[(b << 12) + rr] == l2);
  }
  s2 = s2 && (l2 != 4);
  flag2[gid] = l2 | (s2 ? 8 : 0);
  if (l2 < 4) {
    atomicAdd(&sc[12 + l2], 1);
    if (s2) atomicAdd(&sc[8 + l2], 1);
  }
  __syncthreads();
  if (tid < 16) {
    int view = tid >> 3, kind = (tid >> 2) & 1, cls = tid & 3;
    atomicAdd(&cnts[((view * 2 + kind) * NB + b) * 4 + cls], sc[tid]);
  }
}

// ---------------- K6: masked feature sums (raw f / f_aug) ----------------
__global__ void pb_accum(const float* __restrict__ f, const float* __restrict__ fa,
                         const int* __restrict__ flag1, const int* __restrict__ flag2,
                         float* __restrict__ pacc) {
  int c = threadIdx.x;                 // channel
  int nc = blockIdx.x;                 // n-chunk of 512
  int view = blockIdx.y, b = blockIdx.z;
  const float* src = view ? fa : f;
  const int* flg = (view ? flag2 : flag1) + (b << 12);
  const float* row = src + (((size_t)(b << 8) + c) << 12);   // f[b][c][.]
  float aS0=0, aS1=0, aS2=0, aS3=0, aA0=0, aA1=0, aA2=0, aA3=0;
  int n0 = nc * 512;
#pragma unroll 2
  for (int n = n0; n < n0 + 512; n += 4) {
    float4 v = *(const float4*)(row + n);
    int4 fl = *(const int4*)(flg + n);
#define PB_ACC(val, ff) do { int _l = (ff) & 7; int _f = (ff);                 \
      aA0 += (_l == 0) ? (val) : 0.f; aA1 += (_l == 1) ? (val) : 0.f;          \
      aA2 += (_l == 2) ? (val) : 0.f; aA3 += (_l == 3) ? (val) : 0.f;          \
      aS0 += (_f == 8) ? (val) : 0.f; aS1 += (_f == 9) ? (val) : 0.f;          \
      aS2 += (_f == 10) ? (val) : 0.f; aS3 += (_f == 11) ? (val) : 0.f; } while (0)
    PB_ACC(v.x, fl.x); PB_ACC(v.y, fl.y); PB_ACC(v.z, fl.z); PB_ACC(v.w, fl.w);
#undef PB_ACC
  }
  size_t base = (((size_t)(view * NB + b) * 4) * 2) * NCH + c;   // [view][b][cls][kind][C]
  atomicAdd(&pacc[base + (0 * 2 + 0) * NCH], aS0);
  atomicAdd(&pacc[base + (0 * 2 + 1) * NCH], aA0);
  atomicAdd(&pacc[base + (1 * 2 + 0) * NCH], aS1);
  atomicAdd(&pacc[base + (1 * 2 + 1) * NCH], aA1);
  atomicAdd(&pacc[base + (2 * 2 + 0) * NCH], aS2);
  atomicAdd(&pacc[base + (2 * 2 + 1) * NCH], aA2);
  atomicAdd(&pacc[base + (3 * 2 + 0) * NCH], aS3);
  atomicAdd(&pacc[base + (3 * 2 + 1) * NCH], aA3);
}

// ---------------- K7: select + divide -> d_out ----------------
__global__ void pb_final(const float* __restrict__ pacc, const int* __restrict__ cnts,
                         float* __restrict__ out) {
  int idx = blockIdx.x * 256 + threadIdx.x;      // 0..16383
  int view = idx >> 13, r = idx & 8191;
  int b = r >> 10, cls = (r >> 8) & 3, c = r & 255;
  size_t base = ((((size_t)(view * NB + b) * 4 + cls) * 2) * NCH) + c;
  float sS = pacc[base];
  float sA = pacc[base + NCH];
  int cS = cnts[((view * 2 + 0) * NB + b) * 4 + cls];
  int cA = cnts[((view * 2 + 1) * NB + b) * 4 + cls];
  float v = (cS > 0) ? sS / fmaxf((float)cS, 1.f)
                     : ((cA > 0) ? sA / fmaxf((float)cA, 1.f) : 0.f);
  out[idx] = v;
}

extern "C" void kernel_launch(void* const* d_in, const int* in_sizes, int n_in,
                              void* d_out, int out_size, void* d_ws, size_t ws_size,
                              hipStream_t stream) {
  const float* f   = (const float*)d_in[0];
  const float* fa  = (const float*)d_in[1];
  const int* lab   = (const int*)d_in[2];
  const int* laba  = (const int*)d_in[3];
  float* out = (float*)d_out;
  char* ws = (char*)d_ws;
  if (ws_size < WS_NEEDED) return;   // visible failure instead of corruption

  float* fnT   = (float*)(ws + OFF_FNT);
  float* fanT  = (float*)(ws + OFF_FANT);
  float* rowPV = (float*)(ws + OFF_ROWPV);
  int*   rowPI = (int*)  (ws + OFF_ROWPI);
  float* colPV = (float*)(ws + OFF_COLPV);
  int*   colPI = (int*)  (ws + OFF_COLPI);
  float* dnf   = (float*)(ws + OFF_DNF);
  float* dnfa  = (float*)(ws + OFF_DNFA);
  int*   lab1  = (int*)  (ws + OFF_LAB1);
  int*   lab2  = (int*)  (ws + OFF_LAB2);
  int*   rowT3 = (int*)  (ws + OFF_ROWT3);
  int*   colT3 = (int*)  (ws + OFF_COLT3);
  int*   flag1 = (int*)  (ws + OFF_FLAG1);
  int*   flag2 = (int*)  (ws + OFF_FLAG2);
  int*   cnts  = (int*)  (ws + OFF_CNTS);
  float* pacc  = (float*)(ws + OFF_PACC);

  hipMemsetAsync(ws + OFF_CNTS, 0, 512 + 131072, stream);

  pb_dslab<<<dim3(128, 2), 256, 0, stream>>>(lab, laba, lab1, lab2);
  pb_norm <<<dim3(16, NB, 2), 256, 0, stream>>>(f, fa, dnf, dnfa);
  pb_scale<<<dim3(8192, 2), 256, 0, stream>>>(f, fa, dnf, dnfa, fnT, fanT);
  pb_gemm_top3<<<dim3(32, 32, NB), 256, 0, stream>>>(fnT, fanT, rowPV, rowPI, colPV, colPI);
  pb_merge<<<128, 256, 0, stream>>>(rowPV, rowPI, rowT3);
  pb_merge<<<128, 256, 0, stream>>>(colPV, colPI, colT3);
  pb_stable<<<dim3(16, NB), 256, 0, stream>>>(lab1, lab2, rowT3, colT3, flag1, flag2, cnts);
  pb_accum<<<dim3(8, 2, NB), 256, 0, stream>>>(f, fa, flag1, flag2, pacc);
  pb_final<<<64, 256, 0, stream>>>(pacc, cnts, out);
}